// Round 1
// baseline (284.211 us; speedup 1.0000x reference)
//
#include <hip/hip_runtime.h>

#define BN_EPS 1e-5f
#define ATT_SCALE 0.125f   // 64^-0.5

typedef _Float16 half_t;
typedef _Float16 half8 __attribute__((ext_vector_type(8)));
typedef _Float16 half4 __attribute__((ext_vector_type(4)));
typedef float f32x4 __attribute__((ext_vector_type(4)));

// async global->LDS, 16B per lane; LDS dest = wave-uniform base + lane*16
__device__ __forceinline__ void gll16(const void* g, void* l) {
    __builtin_amdgcn_global_load_lds((const __attribute__((address_space(1))) void*)g,
                                     (__attribute__((address_space(3))) void*)l, 16, 0, 0);
}

// ================= fused prep (BN-fold + weight split) + dw-conv pack =================
__device__ void prep_body(
    int o, int c,
    const float* qg, const float* qb, const float* qm, const float* qv, const float* qpw,
    const float* kg, const float* kbt, const float* km, const float* kvv, const float* kvpw,
    const float* outw,
    half_t* wq, half_t* wkv, half_t* wout, float* bq, float* bkv, float* red)
{
    if (o >= 1536) {   // out_w rows: no BN, just split
        int ro = o - 1536;
        #pragma unroll
        for (int ci = 0; ci < 2; ++ci) {
            int cc = ci * 256 + c;
            float wv = outw[(size_t)ro * 512 + cc];
            half_t hh = (half_t)wv;
            wout[(size_t)ro * 1024 + cc]       = hh;
            wout[(size_t)ro * 1024 + 512 + cc] = (half_t)(wv - (float)hh);
        }
        return;
    }
    const float *g, *b, *m, *v, *w; half_t* we; float* be;
    if (o < 512) {
        g = qg; b = qb; m = qm; v = qv;
        w = qpw + (size_t)o * 256; we = wq + (size_t)o * 512; be = bq + o;
    } else {
        int ro = o - 512;
        g = kg; b = kbt; m = km; v = kvv;
        w = kvpw + (size_t)ro * 256; we = wkv + (size_t)ro * 512; be = bkv + ro;
    }
    float s  = g[c] * rsqrtf(v[c] + BN_EPS);
    float tt = b[c] - m[c] * s;
    float wv = w[c];
    float wsv = wv * s;
    half_t hh = (half_t)wsv;
    we[c]       = hh;
    we[256 + c] = (half_t)(wsv - (float)hh);
    float partial = wv * tt;
    #pragma unroll
    for (int off = 32; off > 0; off >>= 1)
        partial += __shfl_down(partial, off, 64);
    if ((c & 63) == 0) red[c >> 6] = partial;
    __syncthreads();
    if (c == 0) *be = red[0] + red[1] + red[2] + red[3];
}

// dw conv with vectorized padded-LDS window reads.
// sin layout: ch*148 + row*36 + physcol; physcol = logical_col + 2 (logical -2..33).
__device__ void dw_body(
    int rp, int img, float* sin,
    const float* x, const float* y,
    const float* qdw, const float* kvdw,
    half_t* qB, half_t* kvB)
{
    const float* in = (img < 8) ? x + (size_t)img * 256 * 1024
                                : y + (size_t)(img - 8) * 256 * 1024;
    int t = threadIdx.x;
    int ch = t & 63, cg = t >> 6;
    int r0 = 2 * rp - 1;
    // zero pads (physical cols 0,1,34,35) once; staging only writes 2..33
    #pragma unroll
    for (int u = t; u < 1024; u += 256) {
        int c = u >> 4, row = (u >> 2) & 3, pi = u & 3;
        sin[c * 148 + row * 36 + (pi < 2 ? pi : 32 + pi)] = 0.f;
    }
    for (int cc = 0; cc < 4; ++cc) {
        __syncthreads();
        #pragma unroll
        for (int ii = 0; ii < 8; ++ii) {
            int u = ii * 256 + t;            // float4 unit
            int sch = u >> 5, row = (u >> 3) & 3, seg = u & 7;
            int gr = r0 + row;
            float4 v4 = {0.f, 0.f, 0.f, 0.f};
            if (gr >= 0 && gr < 32)
                v4 = *(const float4*)(in + (size_t)(cc * 64 + sch) * 1024 + gr * 32 + seg * 4);
            float* d = &sin[sch * 148 + row * 36 + 2 + seg * 4];  // 8B-aligned
            d[0] = v4.x; d[1] = v4.y; d[2] = v4.z; d[3] = v4.w;
        }
        __syncthreads();
        int gch = cc * 64 + ch;
        float wq9[9], wk9[9];
        #pragma unroll
        for (int i = 0; i < 9; ++i) { wq9[i] = qdw[gch * 9 + i]; wk9[i] = kvdw[gch * 9 + i]; }
        // load 4 rows x 12 floats (physical cg*8 .. cg*8+11 = logical cg*8-2 .. +9)
        float rowv[4][12];
        const float* base = &sin[ch * 148];
        #pragma unroll
        for (int rr = 0; rr < 4; ++rr) {
            *(float4*)&rowv[rr][0] = *(const float4*)(base + rr * 36 + cg * 8);
            *(float4*)&rowv[rr][4] = *(const float4*)(base + rr * 36 + cg * 8 + 4);
            *(float4*)&rowv[rr][8] = *(const float4*)(base + rr * 36 + cg * 8 + 8);
        }
        // q (stride 1): rows 2rp..2rp+1, cols cg*8..+8; tap e = c8+dc+1
        #pragma unroll
        for (int r = 0; r < 2; ++r) {
            #pragma unroll
            for (int c8 = 0; c8 < 8; ++c8) {
                float acc = 0.f;
                #pragma unroll
                for (int dr = 0; dr < 3; ++dr)
                    #pragma unroll
                    for (int dc = 0; dc < 3; ++dc)
                        acc += wq9[dr * 3 + dc] * rowv[r + dr][c8 + dc + 1];
                half_t hh = (half_t)acc;
                size_t p = (size_t)img * 1024 + (2 * rp + r) * 32 + cg * 8 + c8;
                qB[p * 512 + gch]       = hh;
                qB[p * 512 + 256 + gch] = (half_t)(acc - (float)hh);
            }
        }
        // kv (stride 2): row rp, cols cg*4..+4; tap e = 2*c4+dc+1
        #pragma unroll
        for (int c4 = 0; c4 < 4; ++c4) {
            float acc = 0.f;
            #pragma unroll
            for (int dr = 0; dr < 3; ++dr)
                #pragma unroll
                for (int dc = 0; dc < 3; ++dc)
                    acc += wk9[dr * 3 + dc] * rowv[dr][2 * c4 + dc + 1];
            half_t hh = (half_t)acc;
            size_t p = (size_t)img * 256 + rp * 16 + cg * 4 + c4;
            kvB[p * 512 + gch]       = hh;
            kvB[p * 512 + 256 + gch] = (half_t)(acc - (float)hh);
        }
    }
}

__global__ __launch_bounds__(256) void prep_dw_kernel(
    const float* __restrict__ x, const float* __restrict__ y,
    const float* __restrict__ qdw, const float* __restrict__ kvdw,
    const float* __restrict__ qg, const float* __restrict__ qb,
    const float* __restrict__ qm, const float* __restrict__ qv,
    const float* __restrict__ qpw,
    const float* __restrict__ kg, const float* __restrict__ kbt,
    const float* __restrict__ km, const float* __restrict__ kvv,
    const float* __restrict__ kvpw,
    const float* __restrict__ outw,
    half_t* __restrict__ wq, half_t* __restrict__ wkv, half_t* __restrict__ wout,
    float* __restrict__ bq, float* __restrict__ bkv,
    half_t* __restrict__ qB, half_t* __restrict__ kvB)
{
    __shared__ __align__(16) float smem[64 * 148];
    int bx = blockIdx.x;
    if (bx < 256)
        dw_body(bx & 15, bx >> 4, smem, x, y, qdw, kvdw, qB, kvB);
    else
        prep_body(bx - 256, threadIdx.x, qg, qb, qm, qv, qpw,
                  kg, kbt, km, kvv, kvpw, outw, wq, wkv, wout, bq, bkv, smem);
}

// ================= split-f16 MFMA GEMM worker (double-buffered, 1 barrier/chunk) ====
// KC=32. Per chunk: stage A_hi,A_lo,B_hi,B_lo for chunk k+1 after the barrier, compute k.
// A [M][2K] hi|lo, B [N][2K] hi|lo; C = sum_k A*B^T. Ab/Bb pre-offset by m0/n0 (+img).
// MODE 0 (QK): f16 out [(img*8+h)*NPX + n][128]: hi d0, lo 64+d0; (acc+bias[m])*scale
// MODE 1 (V):  f16 out [(img*8+h)*64 + d][512]: hi at m, lo 256+m; acc+bias[n]
//   (MODE 0/1: LDS-transposed epilogue -> coalesced 16B stores)
// MODE 2 (F32): fp32 out [img*256 + m][NPX] = acc + bias[m]  (direct)
template<int MT, int NT, int WGM, int WGN, int NTHR, int MODE>
__device__ __forceinline__ void gemm_worker(
    char* lds, const half_t* Ab, const half_t* Bb,
    void* outBuf, const float* bias,
    int K, int NPX, int img, int m0, int n0, float scale)
{
    constexpr int TM = WGM * MT * 16, TN = WGN * NT * 16;
    constexpr int BUF = (TM + TN) * 128;   // bytes per buffer (A hi/lo + B hi/lo)
    int t = threadIdx.x, w = t >> 6, lane = t & 63, quad = lane >> 4, l15 = lane & 15;
    int wm = w % WGM, wn = w / WGM;
    f32x4 acc[MT][NT] = {};
    const int NC = K / 32;

    auto stage = [&](int kh, int p) {   // kh = k offset in halfs
        char* Ah = lds + p * BUF;
        char* Al = Ah + TM * 64;
        char* Bh = Ah + TM * 128;
        char* Bl = Bh + TN * 64;
        #pragma unroll
        for (int ii = 0; ii < TM * 4 / NTHR; ++ii) {
            int u = ii * NTHR + t;
            int mt = u >> 6, q = (u >> 4) & 3, r = u & 15;
            const half_t* g = Ab + (size_t)(mt * 16 + r) * (2 * K) + kh + q * 8;
            gll16(g,     Ah + (u & ~63) * 16);
            gll16(g + K, Al + (u & ~63) * 16);
        }
        #pragma unroll
        for (int ii = 0; ii < TN * 4 / NTHR; ++ii) {
            int u = ii * NTHR + t;
            int nt = u >> 6, q = (u >> 4) & 3, r = u & 15;
            const half_t* g = Bb + (size_t)(nt * 16 + r) * (2 * K) + kh + q * 8;
            gll16(g,     Bh + (u & ~63) * 16);
            gll16(g + K, Bl + (u & ~63) * 16);
        }
    };

    stage(0, 0);
    for (int kc = 0; kc < NC; ++kc) {
        __syncthreads();                      // buf[kc&1] ready; buf[(kc+1)&1] free
        if (kc + 1 < NC) stage((kc + 1) * 32, (kc + 1) & 1);
        char* Ah = lds + (kc & 1) * BUF;
        char* Al = Ah + TM * 64;
        char* Bh = Ah + TM * 128;
        char* Bl = Bh + TN * 64;
        half8 afh[MT], afl[MT];
        #pragma unroll
        for (int mi = 0; mi < MT; ++mi) {
            afh[mi] = *(half8*)(Ah + (wm * MT + mi) * 1024 + lane * 16);
            afl[mi] = *(half8*)(Al + (wm * MT + mi) * 1024 + lane * 16);
        }
        #pragma unroll
        for (int ni = 0; ni < NT; ++ni) {
            half8 bh = *(half8*)(Bh + (wn * NT + ni) * 1024 + lane * 16);
            half8 bl = *(half8*)(Bl + (wn * NT + ni) * 1024 + lane * 16);
            #pragma unroll
            for (int mi = 0; mi < MT; ++mi) {
                acc[mi][ni] = __builtin_amdgcn_mfma_f32_16x16x32_f16(afh[mi], bh, acc[mi][ni], 0, 0, 0);
                acc[mi][ni] = __builtin_amdgcn_mfma_f32_16x16x32_f16(afh[mi], bl, acc[mi][ni], 0, 0, 0);
                acc[mi][ni] = __builtin_amdgcn_mfma_f32_16x16x32_f16(afl[mi], bh, acc[mi][ni], 0, 0, 0);
            }
        }
    }

    if (MODE == 2) {
        #pragma unroll
        for (int mi = 0; mi < MT; ++mi) {
            int mrow0 = m0 + wm * MT * 16 + mi * 16 + quad * 4;
            #pragma unroll
            for (int ni = 0; ni < NT; ++ni) {
                int col = n0 + wn * NT * 16 + ni * 16 + l15;
                f32x4 a = acc[mi][ni];
                float* op = (float*)outBuf + (size_t)img * 256 * NPX;
                #pragma unroll
                for (int r = 0; r < 4; ++r)
                    op[(size_t)(mrow0 + r) * NPX + col] = a[r] + bias[mrow0 + r];
            }
        }
    } else {
        // LDS-transposed epilogue: TM in 32-row quarters; tbuf [TN][40 floats]
        __syncthreads();
        float* tbuf = (float*)lds;
        constexpr int TP = 40;
        #pragma unroll
        for (int qtr = 0; qtr < TM / 32; ++qtr) {
            #pragma unroll
            for (int mi = 0; mi < MT; ++mi) {
                int rowblk = wm * MT * 16 + mi * 16;
                if (rowblk >= qtr * 32 && rowblk < qtr * 32 + 32) {
                    int mloc = rowblk - qtr * 32 + quad * 4;
                    #pragma unroll
                    for (int ni = 0; ni < NT; ++ni) {
                        int nloc = wn * NT * 16 + ni * 16 + l15;
                        #pragma unroll
                        for (int r = 0; r < 4; ++r) {
                            float vv = acc[mi][ni][r];
                            if (MODE == 0) vv = (vv + bias[m0 + rowblk + quad * 4 + r]) * scale;
                            else           vv = vv + bias[n0 + nloc];
                            tbuf[nloc * TP + mloc + r] = vv;
                        }
                    }
                }
            }
            __syncthreads();
            #pragma unroll
            for (int it = 0; it < (TN * 4) / NTHR; ++it) {
                int u = it * NTHR + t;
                int n = u >> 2, mg = u & 3;
                float vv[8];
                *(float4*)&vv[0] = *(const float4*)&tbuf[n * TP + mg * 8];
                *(float4*)&vv[4] = *(const float4*)&tbuf[n * TP + mg * 8 + 4];
                half8 hv, lv;
                #pragma unroll
                for (int j = 0; j < 8; ++j) {
                    half_t hh = (half_t)vv[j];
                    hv[j] = hh; lv[j] = (half_t)(vv[j] - (float)hh);
                }
                int mglob = m0 + qtr * 32 + mg * 8;
                if (MODE == 0) {
                    int h = mglob >> 6, d0 = mglob & 63;
                    half_t* op = (half_t*)outBuf + ((size_t)(img * 8 + h) * NPX + n0 + n) * 128 + d0;
                    *(half8*)op = hv;
                    *(half8*)(op + 64) = lv;
                } else {
                    int nn = n0 + n, h = nn >> 6, d = nn & 63;
                    half_t* op = (half_t*)outBuf + ((size_t)(img * 8 + h) * 64 + d) * 512 + mglob;
                    *(half8*)op = hv;
                    *(half8*)(op + 256) = lv;
                }
            }
            __syncthreads();
        }
    }
}

// ---- fused q/k/v projection: 48 128x128 tiles/img, 512 threads, dbuf 64KB ----
__global__ __launch_bounds__(512, 4) void qkv_kernel(
    const half_t* __restrict__ wq, const half_t* __restrict__ wkv,
    const half_t* __restrict__ qB, const half_t* __restrict__ kvB,
    const float* __restrict__ bq, const float* __restrict__ bkv,
    half_t* __restrict__ qpr, half_t* __restrict__ kpr, half_t* __restrict__ vpr)
{
    __shared__ __align__(16) char lds[65536];
    int tile = blockIdx.x, img = blockIdx.z;
    if (tile < 32) {        // q': (wq @ dwq + bq)*SCALE  M=512 N=1024 K=256
        int m0 = (tile >> 3) * 128, n0 = (tile & 7) * 128;
        gemm_worker<2, 4, 4, 2, 512, 0>(lds,
            wq + (size_t)m0 * 512,
            qB + (size_t)img * (1024 * 512) + (size_t)n0 * 512,
            qpr, bq, 256, 1024, img, m0, n0, ATT_SCALE);
    } else if (tile < 40) { // k': wkv[0:512] @ dwkv + bkv  M=512 N=256 K=256
        int tt = tile - 32;
        int m0 = (tt >> 1) * 128, n0 = (tt & 1) * 128;
        gemm_worker<2, 4, 4, 2, 512, 0>(lds,
            wkv + (size_t)m0 * 512,
            kvB + (size_t)img * (256 * 512) + (size_t)n0 * 512,
            kpr, bkv, 256, 256, img, m0, n0, 1.0f);
    } else {                // v': (wkv[512:] @ dwkv + bkv)^T  M=256(j) N=512(c) K=256
        int tt = tile - 40;
        int m0 = (tt >> 2) * 128, n0 = (tt & 3) * 128;
        gemm_worker<2, 4, 4, 2, 512, 1>(lds,
            kvB + (size_t)img * (256 * 512) + (size_t)m0 * 512,
            wkv + (size_t)(512 + n0) * 512,
            vpr, bkv + 512, 256, 512, img, m0, n0, 1.0f);
    }
}

// ---- out-proj: 64x128 tiles, 256 threads, dbuf 48KB, 32 tiles/img ----
__global__ __launch_bounds__(256, 3) void out_kernel(
    const half_t* __restrict__ wout, const half_t* __restrict__ attp,
    const float* __restrict__ outb, float* __restrict__ out)
{
    __shared__ __align__(16) char lds[49152];
    int tile = blockIdx.x, img = blockIdx.z;
    int m0 = (tile >> 3) * 64, n0 = (tile & 7) * 128;
    gemm_worker<2, 4, 2, 2, 256, 2>(lds,
        wout + (size_t)m0 * 1024,
        attp + (size_t)img * (1024 * 1024) + (size_t)n0 * 1024,
        out, outb, 512, 1024, img, m0, n0, 1.0f);
}

// ================= attention v2: 256 threads (4 waves x 32 q-rows), 128 q/block ====
// Grid: x = h*16 + img, y = ic.  All 1024 blocks resident (LDS 32KB -> 4 blocks/CU).
// Chunked-streaming over j in 32-row chunks, double-buffered 8KB KV buffers:
//   phase 1: 8 K-chunks, 1 barrier/chunk, stage next chunk after barrier.
//   phase 2: 8 V-chunks, same pattern; per-wave P tiles (no cross-wave use) need
//            no barrier between write and read.
// Each wave owns 32 q-rows (two 16-row MFMA groups) -> every LDS B-frag read
// feeds 6 MFMAs (was 3).  P tiles XOR-swizzled (addr ^= (i>>2&3)<<4) so the
// transposed A-frag b128 reads are bank-balanced.
// LDS map: KV dbuf @0 (2 x 8192); P @16384 + w*4096 ([g 2][plane 2][i 16][j 32]).
// Epilogue: two 16KB rounds (g=0,1) reusing @0, 128-half rows, same XOR swizzle.
__global__ __launch_bounds__(256, 4) void attn_fused(
    const half_t* __restrict__ qb, const half_t* __restrict__ kb,
    const half_t* __restrict__ vb, half_t* __restrict__ att)
{
    __shared__ __align__(16) char lds[32768];
    int ic = blockIdx.y;
    int img = blockIdx.x & 15, h = blockIdx.x >> 4;
    int partner = img ^ 8;
    int t = threadIdx.x, w = t >> 6, lane = t & 63, quad = lane >> 4, l15 = lane & 15;
    const half_t* qp = qb + ((size_t)(img * 8 + h) * 1024 + ic * 128) * 128;
    const half_t* kp = kb + (size_t)(partner * 8 + h) * 256 * 128;
    const half_t* vp = vb + (size_t)(partner * 8 + h) * 64 * 512;

    // Q frags: rows i = w*32 + g*16 + l15 (A-frag m = l15, k = kcs*32 + quad*8 + e)
    half8 qh[2][2], ql[2][2];
    #pragma unroll
    for (int g = 0; g < 2; ++g)
        #pragma unroll
        for (int kcs = 0; kcs < 2; ++kcs) {
            const half_t* qr = qp + (size_t)(w * 32 + g * 16 + l15) * 128 + kcs * 32 + quad * 8;
            qh[g][kcs] = *(const half8*)qr;
            ql[g][kcs] = *(const half8*)(qr + 64);
        }

    // K chunk stage: sb = plane*4 + ntr*2 + kcs (1KB sub-blocks); wave w does sb=w,w+4.
    // lane(quad,l15) -> K[c*32 + ntr*16 + l15][plane*64 + kcs*32 + quad*8 ..+8]
    auto stageK = [&](int c, char* buf) {
        #pragma unroll
        for (int s = 0; s < 2; ++s) {
            int sb = s * 4 + w;
            int plane = sb >> 2, ntr = (sb >> 1) & 1, kcs = sb & 1;
            const half_t* gp = kp + (size_t)(c * 32 + ntr * 16 + l15) * 128
                                  + plane * 64 + kcs * 32 + quad * 8;
            gll16(gp, buf + sb * 1024);
        }
    };
    // V chunk stage: sb = plane*4 + ntv; lane -> V[ntv*16 + l15][plane sel + c*32 + quad*8]
    auto stageV = [&](int c, char* buf) {
        #pragma unroll
        for (int s = 0; s < 2; ++s) {
            int sb = s * 4 + w;
            int plane = sb >> 2, ntv = sb & 3;
            const half_t* gp = vp + (size_t)(ntv * 16 + l15) * 512
                                  + plane * 256 + c * 32 + quad * 8;
            gll16(gp, buf + sb * 1024);
        }
    };

    // ---- phase 1: S[32 i][256 j] per wave, 8 chunks, dbuf ----
    f32x4 sacc[2][16] = {};
    stageK(0, lds);
    #pragma unroll
    for (int c = 0; c < 8; ++c) {
        __syncthreads();                       // buf[c&1] ready; buf[(c+1)&1] free
        char* nb = lds + (((c + 1) & 1) * 8192);
        if (c < 7) stageK(c + 1, nb); else stageV(0, nb);
        const char* buf = lds + ((c & 1) * 8192);
        __builtin_amdgcn_s_setprio(1);
        #pragma unroll
        for (int kcs = 0; kcs < 2; ++kcs)
            #pragma unroll
            for (int ntr = 0; ntr < 2; ++ntr) {
                half8 bh = *(const half8*)(buf + (ntr * 2 + kcs) * 1024 + lane * 16);
                half8 bl = *(const half8*)(buf + 4096 + (ntr * 2 + kcs) * 1024 + lane * 16);
                #pragma unroll
                for (int g = 0; g < 2; ++g) {
                    f32x4 a = sacc[g][c * 2 + ntr];
                    a = __builtin_amdgcn_mfma_f32_16x16x32_f16(qh[g][kcs], bh, a, 0, 0, 0);
                    a = __builtin_amdgcn_mfma_f32_16x16x32_f16(qh[g][kcs], bl, a, 0, 0, 0);
                    a = __builtin_amdgcn_mfma_f32_16x16x32_f16(ql[g][kcs], bh, a, 0, 0, 0);
                    sacc[g][c * 2 + ntr] = a;
                }
            }
        __builtin_amdgcn_s_setprio(0);
    }

    // ---- row max (row i = quad*4 + r; j spans accs x l15) ----
    float mrow[2][4];
    #pragma unroll
    for (int g = 0; g < 2; ++g)
        #pragma unroll
        for (int r = 0; r < 4; ++r) {
            float mx = sacc[g][0][r];
            #pragma unroll
            for (int nt = 1; nt < 16; ++nt) mx = fmaxf(mx, sacc[g][nt][r]);
            #pragma unroll
            for (int off = 1; off < 16; off <<= 1) mx = fmaxf(mx, __shfl_xor(mx, off, 64));
            mrow[g][r] = mx;
        }

    // ---- phase 2: O~[32 i][64 d] per wave; 8 V-chunks, dbuf; per-wave P tiles ----
    char* Pw = lds + 16384 + w * 4096;
    f32x4 oacc[2][4] = {};
    float lsum[2][4] = {};
    #pragma unroll
    for (int c = 0; c < 8; ++c) {
        // exp + split-store P chunk c (own-wave LDS, barrier-free wrt read)
        #pragma unroll
        for (int g = 0; g < 2; ++g)
            #pragma unroll
            for (int ntr = 0; ntr < 2; ++ntr)
                #pragma unroll
                for (int r = 0; r < 4; ++r) {
                    float pv = __expf(sacc[g][c * 2 + ntr][r] - mrow[g][r]);
                    lsum[g][r] += pv;
                    half_t hh = (half_t)pv;
                    int off = (((quad * 4 + r) * 64 + (ntr * 16 + l15) * 2) ^ (quad << 4))
                              + g * 2048;
                    *(half_t*)(Pw + off)        = hh;
                    *(half_t*)(Pw + off + 1024) = (half_t)(pv - (float)hh);
                }
        __syncthreads();                       // V[c] ready in buf[c&1]; buf[(c+1)&1] free
        if (c < 7) stageV(c + 1, lds + (((c + 1) & 1) * 8192));
        const char* buf = lds + ((c & 1) * 8192);
        half8 ph[2], pl[2];
        int roff = (l15 * 64 + quad * 16) ^ (((l15 >> 2) & 3) << 4);
        #pragma unroll
        for (int g = 0; g < 2; ++g) {
            ph[g] = *(const half8*)(Pw + g * 2048 + roff);
            pl[g] = *(const half8*)(Pw + g * 2048 + 1024 + roff);
        }
        __builtin_amdgcn_s_setprio(1);
        #pragma unroll
        for (int ntv = 0; ntv < 4; ++ntv) {
            half8 vh = *(const half8*)(buf + ntv * 1024 + lane * 16);
            half8 vl = *(const half8*)(buf + 4096 + ntv * 1024 + lane * 16);
            #pragma unroll
            for (int g = 0; g < 2; ++g) {
                f32x4 a = oacc[g][ntv];
                a = __builtin_amdgcn_mfma_f32_16x16x32_f16(ph[g], vh, a, 0, 0, 0);
                a = __builtin_amdgcn_mfma_f32_16x16x32_f16(ph[g], vl, a, 0, 0, 0);
                a = __builtin_amdgcn_mfma_f32_16x16x32_f16(pl[g], vh, a, 0, 0, 0);
                oacc[g][ntv] = a;
            }
        }
        __builtin_amdgcn_s_setprio(0);
    }

    // ---- normalize: reduce lsum over the 16 j-lanes ----
    float inv[2][4];
    #pragma unroll
    for (int g = 0; g < 2; ++g)
        #pragma unroll
        for (int r = 0; r < 4; ++r) {
            float s = lsum[g][r];
            #pragma unroll
            for (int off = 1; off < 16; off <<= 1) s += __shfl_xor(s, off, 64);
            inv[g][r] = 1.f / s;
        }

    // ---- epilogue: two 16KB rounds (g-groups), XOR-swizzled rows, 16B stores ----
    #pragma unroll
    for (int g = 0; g < 2; ++g) {
        __syncthreads();                       // KV region (g=0) / prior copy (g=1) done
        #pragma unroll
        for (int ntv = 0; ntv < 4; ++ntv)
            #pragma unroll
            for (int r = 0; r < 4; ++r) {
                float vv = oacc[g][ntv][r] * inv[g][r];
                half_t hh = (half_t)vv;
                int il = w * 16 + quad * 4 + r;    // local row 0..63 within g-round
                int off = (il * 256 + (ntv * 16 + l15) * 2) ^ (quad << 4);
                *(half_t*)(lds + off)       = hh;
                *(half_t*)(lds + off + 128) = (half_t)(vv - (float)hh);
            }
        __syncthreads();
        #pragma unroll
        for (int ii = 0; ii < 4; ++ii) {
            int u = ii * 256 + t;
            int iloc = u >> 4, s16 = u & 15;
            int off = (iloc * 256 + s16 * 16) ^ (((iloc >> 2) & 3) << 4);
            half8 val = *(const half8*)(lds + off);
            int grow = (iloc >> 4) * 32 + g * 16 + (iloc & 15);
            *(half8*)(att + ((size_t)img * 1024 + ic * 128 + grow) * 1024
                      + (s16 >> 3) * 512 + h * 64 + (s16 & 7) * 8) = val;
        }
    }
}

// ================= launch =================
extern "C" void kernel_launch(void* const* d_in, const int* in_sizes, int n_in,
                              void* d_out, int out_size, void* d_ws, size_t ws_size,
                              hipStream_t stream) {
    const float* x    = (const float*)d_in[0];
    const float* y    = (const float*)d_in[1];
    const float* qdw  = (const float*)d_in[2];
    const float* qg   = (const float*)d_in[3];
    const float* qbb  = (const float*)d_in[4];
    const float* qm   = (const float*)d_in[5];
    const float* qv   = (const float*)d_in[6];
    const float* qpw  = (const float*)d_in[7];
    const float* kvdw = (const float*)d_in[8];
    const float* kg   = (const float*)d_in[9];
    const float* kb_  = (const float*)d_in[10];
    const float* km   = (const float*)d_in[11];
    const float* kvv  = (const float*)d_in[12];
    const float* kvpw = (const float*)d_in[13];
    const float* outw = (const float*)d_in[14];
    const float* outb = (const float*)d_in[15];

    char* ws = (char*)d_ws;
    half_t* wq   = (half_t*)(ws);              //  512*512*2  = 524288
    half_t* wkv  = (half_t*)(ws + 524288);     // 1024*512*2  = 1048576
    half_t* wout = (half_t*)(ws + 1572864);    //  256*1024*2 = 524288
    float*  bq   = (float*) (ws + 2097152);
    float*  bkv  = (float*) (ws + 2099200);
    half_t* qpr  = (half_t*)(ws + 2103296);    // 16*8*1024*128*2 = 33554432
    half_t* kpr  = (half_t*)(ws + 35657728);   // 16*8*256*128*2  = 8388608
    half_t* vpr  = (half_t*)(ws + 44046336);   // 16*8*64*512*2   = 8388608
    half_t* qB   = (half_t*)(ws + 52434944);   // 16*1024*512*2   = 16777216
    half_t* kvB  = (half_t*)(ws + 69212160);   // 16*256*512*2    = 4194304
    half_t* attp = (half_t*)(ws + 52434944);   // aliases qB+kvB (dead by attn time): 33554432
    // total 85,989,376 B

    prep_dw_kernel<<<2048, 256, 0, stream>>>(
        x, y, qdw, kvdw, qg, qbb, qm, qv, qpw, kg, kb_, km, kvv, kvpw, outw,
        wq, wkv, wout, bq, bkv, qB, kvB);

    qkv_kernel<<<dim3(48, 1, 16), 512, 0, stream>>>(
        wq, wkv, qB, kvB, bq, bkv, qpr, kpr, vpr);

    attn_fused<<<dim3(128, 8, 1), 256, 0, stream>>>(qpr, kpr, vpr, attp);

    out_kernel<<<dim3(32, 1, 16), 256, 0, stream>>>(wout, attp, outb, (float*)d_out);
}

// Round 2
// 213.350 us; speedup vs baseline: 1.3321x; 1.3321x over previous
//
#include <hip/hip_runtime.h>

#define BN_EPS 1e-5f
#define ATT_SCALE 0.125f   // 64^-0.5

typedef _Float16 half_t;
typedef _Float16 half8 __attribute__((ext_vector_type(8)));
typedef _Float16 half4 __attribute__((ext_vector_type(4)));
typedef float f32x4 __attribute__((ext_vector_type(4)));

// async global->LDS, 16B per lane; LDS dest = wave-uniform base + lane*16
__device__ __forceinline__ void gll16(const void* g, void* l) {
    __builtin_amdgcn_global_load_lds((const __attribute__((address_space(1))) void*)g,
                                     (__attribute__((address_space(3))) void*)l, 16, 0, 0);
}

// ================= fused prep (BN-fold + weight split) + dw-conv pack =================
__device__ void prep_body(
    int o, int c,
    const float* qg, const float* qb, const float* qm, const float* qv, const float* qpw,
    const float* kg, const float* kbt, const float* km, const float* kvv, const float* kvpw,
    const float* outw,
    half_t* wq, half_t* wkv, half_t* wout, float* bq, float* bkv, float* red)
{
    if (o >= 1536) {   // out_w rows: no BN, just split
        int ro = o - 1536;
        #pragma unroll
        for (int ci = 0; ci < 2; ++ci) {
            int cc = ci * 256 + c;
            float wv = outw[(size_t)ro * 512 + cc];
            half_t hh = (half_t)wv;
            wout[(size_t)ro * 1024 + cc]       = hh;
            wout[(size_t)ro * 1024 + 512 + cc] = (half_t)(wv - (float)hh);
        }
        return;
    }
    const float *g, *b, *m, *v, *w; half_t* we; float* be;
    if (o < 512) {
        g = qg; b = qb; m = qm; v = qv;
        w = qpw + (size_t)o * 256; we = wq + (size_t)o * 512; be = bq + o;
    } else {
        int ro = o - 512;
        g = kg; b = kbt; m = km; v = kvv;
        w = kvpw + (size_t)ro * 256; we = wkv + (size_t)ro * 512; be = bkv + ro;
    }
    float s  = g[c] * rsqrtf(v[c] + BN_EPS);
    float tt = b[c] - m[c] * s;
    float wv = w[c];
    float wsv = wv * s;
    half_t hh = (half_t)wsv;
    we[c]       = hh;
    we[256 + c] = (half_t)(wsv - (float)hh);
    float partial = wv * tt;
    #pragma unroll
    for (int off = 32; off > 0; off >>= 1)
        partial += __shfl_down(partial, off, 64);
    if ((c & 63) == 0) red[c >> 6] = partial;
    __syncthreads();
    if (c == 0) *be = red[0] + red[1] + red[2] + red[3];
}

// dw conv with vectorized padded-LDS window reads.
// sin layout: ch*148 + row*36 + physcol; physcol = logical_col + 2 (logical -2..33).
__device__ void dw_body(
    int rp, int img, float* sin,
    const float* x, const float* y,
    const float* qdw, const float* kvdw,
    half_t* qB, half_t* kvB)
{
    const float* in = (img < 8) ? x + (size_t)img * 256 * 1024
                                : y + (size_t)(img - 8) * 256 * 1024;
    int t = threadIdx.x;
    int ch = t & 63, cg = t >> 6;
    int r0 = 2 * rp - 1;
    // zero pads (physical cols 0,1,34,35) once; staging only writes 2..33
    #pragma unroll
    for (int u = t; u < 1024; u += 256) {
        int c = u >> 4, row = (u >> 2) & 3, pi = u & 3;
        sin[c * 148 + row * 36 + (pi < 2 ? pi : 32 + pi)] = 0.f;
    }
    for (int cc = 0; cc < 4; ++cc) {
        __syncthreads();
        #pragma unroll
        for (int ii = 0; ii < 8; ++ii) {
            int u = ii * 256 + t;            // float4 unit
            int sch = u >> 5, row = (u >> 3) & 3, seg = u & 7;
            int gr = r0 + row;
            float4 v4 = {0.f, 0.f, 0.f, 0.f};
            if (gr >= 0 && gr < 32)
                v4 = *(const float4*)(in + (size_t)(cc * 64 + sch) * 1024 + gr * 32 + seg * 4);
            float* d = &sin[sch * 148 + row * 36 + 2 + seg * 4];  // 8B-aligned
            d[0] = v4.x; d[1] = v4.y; d[2] = v4.z; d[3] = v4.w;
        }
        __syncthreads();
        int gch = cc * 64 + ch;
        float wq9[9], wk9[9];
        #pragma unroll
        for (int i = 0; i < 9; ++i) { wq9[i] = qdw[gch * 9 + i]; wk9[i] = kvdw[gch * 9 + i]; }
        // load 4 rows x 12 floats (physical cg*8 .. cg*8+11 = logical cg*8-2 .. +9)
        float rowv[4][12];
        const float* base = &sin[ch * 148];
        #pragma unroll
        for (int rr = 0; rr < 4; ++rr) {
            *(float4*)&rowv[rr][0] = *(const float4*)(base + rr * 36 + cg * 8);
            *(float4*)&rowv[rr][4] = *(const float4*)(base + rr * 36 + cg * 8 + 4);
            *(float4*)&rowv[rr][8] = *(const float4*)(base + rr * 36 + cg * 8 + 8);
        }
        // q (stride 1): rows 2rp..2rp+1, cols cg*8..+8; tap e = c8+dc+1
        #pragma unroll
        for (int r = 0; r < 2; ++r) {
            #pragma unroll
            for (int c8 = 0; c8 < 8; ++c8) {
                float acc = 0.f;
                #pragma unroll
                for (int dr = 0; dr < 3; ++dr)
                    #pragma unroll
                    for (int dc = 0; dc < 3; ++dc)
                        acc += wq9[dr * 3 + dc] * rowv[r + dr][c8 + dc + 1];
                half_t hh = (half_t)acc;
                size_t p = (size_t)img * 1024 + (2 * rp + r) * 32 + cg * 8 + c8;
                qB[p * 512 + gch]       = hh;
                qB[p * 512 + 256 + gch] = (half_t)(acc - (float)hh);
            }
        }
        // kv (stride 2): row rp, cols cg*4..+4; tap e = 2*c4+dc+1
        #pragma unroll
        for (int c4 = 0; c4 < 4; ++c4) {
            float acc = 0.f;
            #pragma unroll
            for (int dr = 0; dr < 3; ++dr)
                #pragma unroll
                for (int dc = 0; dc < 3; ++dc)
                    acc += wk9[dr * 3 + dc] * rowv[dr][2 * c4 + dc + 1];
            half_t hh = (half_t)acc;
            size_t p = (size_t)img * 256 + rp * 16 + cg * 4 + c4;
            kvB[p * 512 + gch]       = hh;
            kvB[p * 512 + 256 + gch] = (half_t)(acc - (float)hh);
        }
    }
}

__global__ __launch_bounds__(256) void prep_dw_kernel(
    const float* __restrict__ x, const float* __restrict__ y,
    const float* __restrict__ qdw, const float* __restrict__ kvdw,
    const float* __restrict__ qg, const float* __restrict__ qb,
    const float* __restrict__ qm, const float* __restrict__ qv,
    const float* __restrict__ qpw,
    const float* __restrict__ kg, const float* __restrict__ kbt,
    const float* __restrict__ km, const float* __restrict__ kvv,
    const float* __restrict__ kvpw,
    const float* __restrict__ outw,
    half_t* __restrict__ wq, half_t* __restrict__ wkv, half_t* __restrict__ wout,
    float* __restrict__ bq, float* __restrict__ bkv,
    half_t* __restrict__ qB, half_t* __restrict__ kvB)
{
    __shared__ __align__(16) float smem[64 * 148];
    int bx = blockIdx.x;
    if (bx < 256)
        dw_body(bx & 15, bx >> 4, smem, x, y, qdw, kvdw, qB, kvB);
    else
        prep_body(bx - 256, threadIdx.x, qg, qb, qm, qv, qpw,
                  kg, kbt, km, kvv, kvpw, outw, wq, wkv, wout, bq, bkv, smem);
}

// ================= split-f16 MFMA GEMM worker (double-buffered, 1 barrier/chunk) ====
// KC=32. Per chunk: stage A_hi,A_lo,B_hi,B_lo for chunk k+1 after the barrier, compute k.
// A [M][2K] hi|lo, B [N][2K] hi|lo; C = sum_k A*B^T. Ab/Bb pre-offset by m0/n0 (+img).
// MODE 0 (QK): f16 out [(img*8+h)*NPX + n][128]: hi d0, lo 64+d0; (acc+bias[m])*scale
// MODE 1 (V):  fragment-order V^T for attn: per (img,h): 8 j-chunks x 8192B,
//   chunk: [plane 2][mt 4][kk 2][lane 64][8B]  (lane=(quad,l15): V^T[mt*16+l15][kk*16+quad*4..+3])
// MODE 2 (F32): fp32 out [img*256 + m][NPX] = acc + bias[m]  (direct)
template<int MT, int NT, int WGM, int WGN, int NTHR, int MODE>
__device__ __forceinline__ void gemm_worker(
    char* lds, const half_t* Ab, const half_t* Bb,
    void* outBuf, const float* bias,
    int K, int NPX, int img, int m0, int n0, float scale)
{
    constexpr int TM = WGM * MT * 16, TN = WGN * NT * 16;
    constexpr int BUF = (TM + TN) * 128;   // bytes per buffer (A hi/lo + B hi/lo)
    int t = threadIdx.x, w = t >> 6, lane = t & 63, quad = lane >> 4, l15 = lane & 15;
    int wm = w % WGM, wn = w / WGM;
    f32x4 acc[MT][NT] = {};
    const int NC = K / 32;

    auto stage = [&](int kh, int p) {   // kh = k offset in halfs
        char* Ah = lds + p * BUF;
        char* Al = Ah + TM * 64;
        char* Bh = Ah + TM * 128;
        char* Bl = Bh + TN * 64;
        #pragma unroll
        for (int ii = 0; ii < TM * 4 / NTHR; ++ii) {
            int u = ii * NTHR + t;
            int mt = u >> 6, q = (u >> 4) & 3, r = u & 15;
            const half_t* g = Ab + (size_t)(mt * 16 + r) * (2 * K) + kh + q * 8;
            gll16(g,     Ah + (u & ~63) * 16);
            gll16(g + K, Al + (u & ~63) * 16);
        }
        #pragma unroll
        for (int ii = 0; ii < TN * 4 / NTHR; ++ii) {
            int u = ii * NTHR + t;
            int nt = u >> 6, q = (u >> 4) & 3, r = u & 15;
            const half_t* g = Bb + (size_t)(nt * 16 + r) * (2 * K) + kh + q * 8;
            gll16(g,     Bh + (u & ~63) * 16);
            gll16(g + K, Bl + (u & ~63) * 16);
        }
    };

    stage(0, 0);
    for (int kc = 0; kc < NC; ++kc) {
        __syncthreads();                      // buf[kc&1] ready; buf[(kc+1)&1] free
        if (kc + 1 < NC) stage((kc + 1) * 32, (kc + 1) & 1);
        char* Ah = lds + (kc & 1) * BUF;
        char* Al = Ah + TM * 64;
        char* Bh = Ah + TM * 128;
        char* Bl = Bh + TN * 64;
        half8 afh[MT], afl[MT];
        #pragma unroll
        for (int mi = 0; mi < MT; ++mi) {
            afh[mi] = *(half8*)(Ah + (wm * MT + mi) * 1024 + lane * 16);
            afl[mi] = *(half8*)(Al + (wm * MT + mi) * 1024 + lane * 16);
        }
        #pragma unroll
        for (int ni = 0; ni < NT; ++ni) {
            half8 bh = *(half8*)(Bh + (wn * NT + ni) * 1024 + lane * 16);
            half8 bl = *(half8*)(Bl + (wn * NT + ni) * 1024 + lane * 16);
            #pragma unroll
            for (int mi = 0; mi < MT; ++mi) {
                acc[mi][ni] = __builtin_amdgcn_mfma_f32_16x16x32_f16(afh[mi], bh, acc[mi][ni], 0, 0, 0);
                acc[mi][ni] = __builtin_amdgcn_mfma_f32_16x16x32_f16(afh[mi], bl, acc[mi][ni], 0, 0, 0);
                acc[mi][ni] = __builtin_amdgcn_mfma_f32_16x16x32_f16(afl[mi], bh, acc[mi][ni], 0, 0, 0);
            }
        }
    }

    if (MODE == 2) {
        #pragma unroll
        for (int mi = 0; mi < MT; ++mi) {
            int mrow0 = m0 + wm * MT * 16 + mi * 16 + quad * 4;
            #pragma unroll
            for (int ni = 0; ni < NT; ++ni) {
                int col = n0 + wn * NT * 16 + ni * 16 + l15;
                f32x4 a = acc[mi][ni];
                float* op = (float*)outBuf + (size_t)img * 256 * NPX;
                #pragma unroll
                for (int r = 0; r < 4; ++r)
                    op[(size_t)(mrow0 + r) * NPX + col] = a[r] + bias[mrow0 + r];
            }
        }
    } else {
        // LDS-transposed epilogue: TM in 32-row quarters; tbuf [TN][40 floats]
        __syncthreads();
        float* tbuf = (float*)lds;
        constexpr int TP = 40;
        #pragma unroll
        for (int qtr = 0; qtr < TM / 32; ++qtr) {
            #pragma unroll
            for (int mi = 0; mi < MT; ++mi) {
                int rowblk = wm * MT * 16 + mi * 16;
                if (rowblk >= qtr * 32 && rowblk < qtr * 32 + 32) {
                    int mloc = rowblk - qtr * 32 + quad * 4;
                    #pragma unroll
                    for (int ni = 0; ni < NT; ++ni) {
                        int nloc = wn * NT * 16 + ni * 16 + l15;
                        #pragma unroll
                        for (int r = 0; r < 4; ++r) {
                            float vv = acc[mi][ni][r];
                            if (MODE == 0) vv = (vv + bias[m0 + rowblk + quad * 4 + r]) * scale;
                            else           vv = vv + bias[n0 + nloc];
                            tbuf[nloc * TP + mloc + r] = vv;
                        }
                    }
                }
            }
            __syncthreads();
            #pragma unroll
            for (int it = 0; it < (TN * 4) / NTHR; ++it) {
                int u = it * NTHR + t;
                int n = u >> 2, mg = u & 3;
                float vv[8];
                *(float4*)&vv[0] = *(const float4*)&tbuf[n * TP + mg * 8];
                *(float4*)&vv[4] = *(const float4*)&tbuf[n * TP + mg * 8 + 4];
                half8 hv, lv;
                #pragma unroll
                for (int j = 0; j < 8; ++j) {
                    half_t hh = (half_t)vv[j];
                    hv[j] = hh; lv[j] = (half_t)(vv[j] - (float)hh);
                }
                int mglob = m0 + qtr * 32 + mg * 8;
                if (MODE == 0) {
                    int h = mglob >> 6, d0 = mglob & 63;
                    half_t* op = (half_t*)outBuf + ((size_t)(img * 8 + h) * NPX + n0 + n) * 128 + d0;
                    *(half8*)op = hv;
                    *(half8*)(op + 64) = lv;
                } else {
                    // fragment-order V^T write (see attn stageV/PV reads).
                    // element (channel nn -> h,d ; pixel j): halfs offset =
                    // (img*8+h)*32768 + (j>>5)*4096 + plane*2048 + mt*512 + kk*256 + quad*64 + l15*4 + (j&3)
                    int nn = n0 + n, h = nn >> 6, d = nn & 63;
                    int j0 = mglob;                       // multiple of 8
                    half_t* op = (half_t*)outBuf + (size_t)(img * 8 + h) * 32768
                               + (j0 >> 5) * 4096 + ((d >> 4) & 3) * 512 + ((j0 >> 4) & 1) * 256
                               + ((j0 >> 2) & 3) * 64 + (d & 15) * 4;
                    half4 a0 = {hv[0], hv[1], hv[2], hv[3]};
                    half4 a1 = {hv[4], hv[5], hv[6], hv[7]};
                    half4 b0 = {lv[0], lv[1], lv[2], lv[3]};
                    half4 b1 = {lv[4], lv[5], lv[6], lv[7]};
                    *(half4*)op               = a0;   // j0..j0+3   (quad q0)
                    *(half4*)(op + 64)        = a1;   // j0+4..j0+7 (quad q0+1)
                    *(half4*)(op + 2048)      = b0;   // lo plane
                    *(half4*)(op + 2048 + 64) = b1;
                }
            }
            __syncthreads();
        }
    }
}

// ---- fused q/k/v projection: 48 128x128 tiles/img, 512 threads, dbuf 64KB ----
__global__ __launch_bounds__(512, 4) void qkv_kernel(
    const half_t* __restrict__ wq, const half_t* __restrict__ wkv,
    const half_t* __restrict__ qB, const half_t* __restrict__ kvB,
    const float* __restrict__ bq, const float* __restrict__ bkv,
    half_t* __restrict__ qpr, half_t* __restrict__ kpr, half_t* __restrict__ vpr)
{
    __shared__ __align__(16) char lds[65536];
    int tile = blockIdx.x, img = blockIdx.z;
    if (tile < 32) {        // q': (wq @ dwq + bq)*SCALE  M=512 N=1024 K=256
        int m0 = (tile >> 3) * 128, n0 = (tile & 7) * 128;
        gemm_worker<2, 4, 4, 2, 512, 0>(lds,
            wq + (size_t)m0 * 512,
            qB + (size_t)img * (1024 * 512) + (size_t)n0 * 512,
            qpr, bq, 256, 1024, img, m0, n0, ATT_SCALE);
    } else if (tile < 40) { // k': wkv[0:512] @ dwkv + bkv  M=512 N=256 K=256
        int tt = tile - 32;
        int m0 = (tt >> 1) * 128, n0 = (tt & 1) * 128;
        gemm_worker<2, 4, 4, 2, 512, 0>(lds,
            wkv + (size_t)m0 * 512,
            kvB + (size_t)img * (256 * 512) + (size_t)n0 * 512,
            kpr, bkv, 256, 256, img, m0, n0, 1.0f);
    } else {                // v': (wkv[512:] @ dwkv + bkv)^T  M=256(j) N=512(c) K=256
        int tt = tile - 40;
        int m0 = (tt >> 2) * 128, n0 = (tt & 3) * 128;
        gemm_worker<2, 4, 4, 2, 512, 1>(lds,
            kvB + (size_t)img * (256 * 512) + (size_t)m0 * 512,
            wkv + (size_t)(512 + n0) * 512,
            vpr, bkv + 512, 256, 512, img, m0, n0, 1.0f);
    }
}

// ---- out-proj: 64x128 tiles, 256 threads, dbuf 48KB, 32 tiles/img ----
__global__ __launch_bounds__(256, 3) void out_kernel(
    const half_t* __restrict__ wout, const half_t* __restrict__ attp,
    const float* __restrict__ outb, float* __restrict__ out)
{
    __shared__ __align__(16) char lds[49152];
    int tile = blockIdx.x, img = blockIdx.z;
    int m0 = (tile >> 3) * 64, n0 = (tile & 7) * 128;
    gemm_worker<2, 4, 2, 2, 256, 2>(lds,
        wout + (size_t)m0 * 1024,
        attp + (size_t)img * (1024 * 1024) + (size_t)n0 * 1024,
        out, outb, 512, 1024, img, m0, n0, 1.0f);
}

// ================= attention v3: swapped-operand, zero-LDS softmax =================
// 256 threads = 4 waves x 16 q-rows -> 64 q/block. Grid: x = h*16+img, y = ic2 (16).
// Phase 1: S^T = MFMA32(A=K, B=Q): lane holds S^T[j=quad*4+r][i=l15]; K streamed in
//   8 x 8KB fragment-major chunks (dbuf, 1 barrier/chunk), reads linear (no conflicts).
// Softmax: row-max/sum over j are per-lane + 2 shfl_xor (quads); inv is lane-local.
// Phase 2: O^T = MFMA16(A=V^T, B=P^T). KEY IDENTITY: the 16x16x16 B-frag layout
//   (n=lane&15, k=(lane>>4)*4+e) == the C/D layout (col=lane&15, row=(lane>>4)*4+reg),
//   so exp(sacc) IS the P^T operand in-register -> no P LDS round-trip at all.
//   V pre-tiled in global (qkv MODE 1) to fragment order -> staging = straight 8KB DMA,
//   PV A-reads = contiguous b64.
// LDS: 2 x 8KB dbuf; epilogue reuses (64 rows x 132 halfs = 16896B). Total 17408B.
// Regs: sacc[16](64) + oacc[4](16) + Q(16) + temps ~ 105 -> fits 128 @ 4 blocks/CU.
__global__ __launch_bounds__(256, 4) void attn_fused(
    const half_t* __restrict__ qb, const half_t* __restrict__ kb,
    const half_t* __restrict__ vb, half_t* __restrict__ att)
{
    __shared__ __align__(16) char lds[17408];
    int ic2 = blockIdx.y;
    int img = blockIdx.x & 15, h = blockIdx.x >> 4;
    int partner = img ^ 8;
    int t = threadIdx.x, w = t >> 6, lane = t & 63, quad = lane >> 4, l15 = lane & 15;
    const half_t* qp = qb + ((size_t)(img * 8 + h) * 1024 + ic2 * 64) * 128;
    const half_t* kp = kb + (size_t)(partner * 8 + h) * 256 * 128;
    const half_t* vp = vb + (size_t)(partner * 8 + h) * 32768;   // fragment-order tiles

    // Q frags (B-side): rows i = w*16 + l15; k = kcs*32 + quad*8 (+64 for lo plane)
    half8 qh[2], ql[2];
    #pragma unroll
    for (int kcs = 0; kcs < 2; ++kcs) {
        const half_t* qr = qp + (size_t)(w * 16 + l15) * 128 + kcs * 32 + quad * 8;
        qh[kcs] = *(const half8*)qr;
        ql[kcs] = *(const half8*)(qr + 64);
    }

    // K chunk (8KB): fragment-major sub-blocks sb = plane*4 + ntr*2 + kcs (1KB),
    // interior lane*16 = K[c*32 + ntr*16 + l15][plane*64 + kcs*32 + quad*8 ..+8]
    auto stageK = [&](int c, char* buf) {
        #pragma unroll
        for (int s = 0; s < 2; ++s) {
            int u = s * 256 + t;
            int sb = u >> 6, li = u & 63;
            int plane = sb >> 2, ntr = (sb >> 1) & 1, kcs = sb & 1;
            const half_t* g = kp + (size_t)(c * 32 + ntr * 16 + (li & 15)) * 128
                                 + plane * 64 + kcs * 32 + (li >> 4) * 8;
            gll16(g, buf + (u & ~63) * 16);
        }
    };
    // V chunk (8KB): global already fragment-order -> straight copy
    auto stageV = [&](int c, char* buf) {
        #pragma unroll
        for (int s = 0; s < 2; ++s) {
            int u = s * 256 + t;
            gll16(vp + (size_t)c * 4096 + u * 8, buf + (u & ~63) * 16);
        }
    };

    // ---- phase 1: S^T, 8 chunks, dbuf ----
    f32x4 sacc[16] = {};
    stageK(0, lds);
    #pragma unroll
    for (int c = 0; c < 8; ++c) {
        __syncthreads();                         // buf[c&1] ready; buf[(c+1)&1] free
        char* nb = lds + (((c + 1) & 1) * 8192);
        if (c < 7) stageK(c + 1, nb); else stageV(0, nb);
        const char* buf = lds + ((c & 1) * 8192);
        __builtin_amdgcn_s_setprio(1);
        #pragma unroll
        for (int kcs = 0; kcs < 2; ++kcs)
            #pragma unroll
            for (int ntr = 0; ntr < 2; ++ntr) {
                half8 kh = *(const half8*)(buf + (ntr * 2 + kcs) * 1024 + lane * 16);
                half8 kl = *(const half8*)(buf + 4096 + (ntr * 2 + kcs) * 1024 + lane * 16);
                f32x4 s = sacc[c * 2 + ntr];
                s = __builtin_amdgcn_mfma_f32_16x16x32_f16(kh, qh[kcs], s, 0, 0, 0);
                s = __builtin_amdgcn_mfma_f32_16x16x32_f16(kh, ql[kcs], s, 0, 0, 0);
                s = __builtin_amdgcn_mfma_f32_16x16x32_f16(kl, qh[kcs], s, 0, 0, 0);
                sacc[c * 2 + ntr] = s;
            }
        __builtin_amdgcn_s_setprio(0);
    }

    // ---- row max over j: per-lane (r x 16 tiles) then across quads ----
    float mx = sacc[0][0];
    #pragma unroll
    for (int ti = 0; ti < 16; ++ti)
        #pragma unroll
        for (int r = 0; r < 4; ++r) mx = fmaxf(mx, sacc[ti][r]);
    mx = fmaxf(mx, __shfl_xor(mx, 16, 64));
    mx = fmaxf(mx, __shfl_xor(mx, 32, 64));

    // ---- phase 2: O^T += V^T x P^T, 8 chunks, dbuf; P built in-register ----
    f32x4 oacc[4] = {};
    float lsum = 0.f;
    #pragma unroll
    for (int c = 0; c < 8; ++c) {
        half4 pb[2][2];   // [kk][hi/lo]
        #pragma unroll
        for (int kk = 0; kk < 2; ++kk) {
            f32x4 s = sacc[c * 2 + kk];
            #pragma unroll
            for (int e = 0; e < 4; ++e) {
                float pv = __expf(s[e] - mx);
                lsum += pv;
                half_t hh = (half_t)pv;
                pb[kk][0][e] = hh;
                pb[kk][1][e] = (half_t)(pv - (float)hh);
            }
        }
        __syncthreads();                         // V[c] ready in buf[c&1]
        if (c < 7) stageV(c + 1, lds + (((c + 1) & 1) * 8192));
        const char* buf = lds + ((c & 1) * 8192);
        __builtin_amdgcn_s_setprio(1);
        #pragma unroll
        for (int mt = 0; mt < 4; ++mt) {
            #pragma unroll
            for (int kk = 0; kk < 2; ++kk) {
                half4 vh = *(const half4*)(buf + (mt * 2 + kk) * 512 + lane * 8);
                half4 vl = *(const half4*)(buf + 4096 + (mt * 2 + kk) * 512 + lane * 8);
                f32x4 o = oacc[mt];
                o = __builtin_amdgcn_mfma_f32_16x16x16f16(vh, pb[kk][0], o, 0, 0, 0);
                o = __builtin_amdgcn_mfma_f32_16x16x16f16(vh, pb[kk][1], o, 0, 0, 0);
                o = __builtin_amdgcn_mfma_f32_16x16x16f16(vl, pb[kk][0], o, 0, 0, 0);
                oacc[mt] = o;
            }
        }
        __builtin_amdgcn_s_setprio(0);
    }

    // ---- normalize: lsum over quads; inv lane-local (i = l15) ----
    lsum += __shfl_xor(lsum, 16, 64);
    lsum += __shfl_xor(lsum, 32, 64);
    float inv = 1.f / lsum;

    // ---- epilogue: O^T -> [i][hi 64 | lo 64] rows in LDS, coalesced 16B stores ----
    __syncthreads();
    #pragma unroll
    for (int mt = 0; mt < 4; ++mt)
        #pragma unroll
        for (int r = 0; r < 4; ++r) {
            float vv = oacc[mt][r] * inv;
            half_t hh = (half_t)vv;
            int row = w * 16 + l15;
            int d = mt * 16 + quad * 4 + r;
            *(half_t*)(lds + (row * 132 + d) * 2)      = hh;
            *(half_t*)(lds + (row * 132 + 64 + d) * 2) = (half_t)(vv - (float)hh);
        }
    __syncthreads();
    #pragma unroll
    for (int ii = 0; ii < 4; ++ii) {
        int u = ii * 256 + t;
        int i = u >> 4, s16 = u & 15;
        half8 val = *(const half8*)(lds + (i * 132 + (s16 >> 3) * 64 + (s16 & 7) * 8) * 2);
        *(half8*)(att + ((size_t)img * 1024 + ic2 * 64 + i) * 1024
                  + (s16 >> 3) * 512 + h * 64 + (s16 & 7) * 8) = val;
    }
}

// ================= launch =================
extern "C" void kernel_launch(void* const* d_in, const int* in_sizes, int n_in,
                              void* d_out, int out_size, void* d_ws, size_t ws_size,
                              hipStream_t stream) {
    const float* x    = (const float*)d_in[0];
    const float* y    = (const float*)d_in[1];
    const float* qdw  = (const float*)d_in[2];
    const float* qg   = (const float*)d_in[3];
    const float* qbb  = (const float*)d_in[4];
    const float* qm   = (const float*)d_in[5];
    const float* qv   = (const float*)d_in[6];
    const float* qpw  = (const float*)d_in[7];
    const float* kvdw = (const float*)d_in[8];
    const float* kg   = (const float*)d_in[9];
    const float* kb_  = (const float*)d_in[10];
    const float* km   = (const float*)d_in[11];
    const float* kvv  = (const float*)d_in[12];
    const float* kvpw = (const float*)d_in[13];
    const float* outw = (const float*)d_in[14];
    const float* outb = (const float*)d_in[15];

    char* ws = (char*)d_ws;
    half_t* wq   = (half_t*)(ws);              //  512*512*2  = 524288
    half_t* wkv  = (half_t*)(ws + 524288);     // 1024*512*2  = 1048576
    half_t* wout = (half_t*)(ws + 1572864);    //  256*1024*2 = 524288
    float*  bq   = (float*) (ws + 2097152);
    float*  bkv  = (float*) (ws + 2099200);
    half_t* qpr  = (half_t*)(ws + 2103296);    // 16*8*1024*128*2 = 33554432
    half_t* kpr  = (half_t*)(ws + 35657728);   // 16*8*256*128*2  = 8388608
    half_t* vpr  = (half_t*)(ws + 44046336);   // 16*8*8*8192     = 8388608 (fragment-order)
    half_t* qB   = (half_t*)(ws + 52434944);   // 16*1024*512*2   = 16777216
    half_t* kvB  = (half_t*)(ws + 69212160);   // 16*256*512*2    = 4194304
    half_t* attp = (half_t*)(ws + 52434944);   // aliases qB+kvB (dead by attn time): 33554432
    // total 85,989,376 B

    prep_dw_kernel<<<2048, 256, 0, stream>>>(
        x, y, qdw, kvdw, qg, qbb, qm, qv, qpw, kg, kb_, km, kvv, kvpw, outw,
        wq, wkv, wout, bq, bkv, qB, kvB);

    qkv_kernel<<<dim3(48, 1, 16), 512, 0, stream>>>(
        wq, wkv, qB, kvB, bq, bkv, qpr, kpr, vpr);

    attn_fused<<<dim3(128, 16, 1), 256, 0, stream>>>(qpr, kpr, vpr, attp);

    out_kernel<<<dim3(32, 1, 16), 256, 0, stream>>>(wout, attp, outb, (float*)d_out);
}